// Round 5
// baseline (256.413 us; speedup 1.0000x reference)
//
#include <hip/hip_runtime.h>

#define NB 32
#define CC 3
#define HH 512
#define WW 512
#define KS 25
#define PAD 12
#define HT 8                  // output rows per block (full 512-wide strip)
#define LDSW 536              // 12 halo + 512 + 12 halo floats per LDS row

__device__ __forceinline__ float clamp01(float v) {
    return fminf(fmaxf(v, 0.0f), 1.0f);
}

__global__ __launch_bounds__(256, 8) void gblur_fused(const float* __restrict__ x,
                                                      float* __restrict__ out) {
    // weights as compile-time literals (indexed only by unrolled constants)
    constexpr float W[KS] = {
        0.02181520f, 0.02514307f, 0.02862302f, 0.03218484f, 0.03574584f,
        0.03921371f, 0.04249020f, 0.04547544f, 0.04807347f, 0.05019624f,
        0.05176967f, 0.05273727f, 0.05306384f, 0.05273727f, 0.05176967f,
        0.05019624f, 0.04807347f, 0.04547544f, 0.04249020f, 0.03921371f,
        0.03574584f, 0.03218484f, 0.02862302f, 0.02514307f, 0.02181520f};

    __shared__ float tile[HT * LDSW];   // 17,152 B

    int tid = threadIdx.x;

    // zero left/right halos: 8 rows x 24 floats = 192 writes (disjoint from
    // the vertical-stage writes; covered by the single __syncthreads below)
    if (tid < HT * 2 * PAD) {
        int r = tid / (2 * PAD);
        int k = tid - r * (2 * PAD);
        tile[r * LDSW + (k < PAD ? k : 512 + k)] = 0.0f;
    }

    // ---- block mapping with bijective XCD swizzle (6144 % 8 == 0) ----
    int b = blockIdx.x;
    const int nwg = NB * CC * (HH / HT);     // 6144
    int per = nwg >> 3;
    int swz = (b & 7) * per + (b >> 3);
    int plane = swz >> 6;                    // 64 strips per plane
    int strip = swz & 63;
    int r0 = strip * HT;

    const float* ibase = x + (long)plane * (HH * WW);
    float*       obase = out + (long)plane * (HH * WW);

    // ---- vertical stage: thread = (float4 col, 4-row group) ----
    int col4 = tid & 127;                    // consecutive lanes -> coalesced f4
    int rg = (tid >> 7) * 4;                 // 0 or 4; wave-uniform
    const float* ip = ibase + col4 * 4;

    float4 acc0 = make_float4(0.f, 0.f, 0.f, 0.f);
    float4 acc1 = acc0, acc2 = acc0, acc3 = acc0;

#pragma unroll
    for (int r = 0; r < 4 + KS - 1; ++r) {   // 28 input rows
        int rr = r0 + rg - PAD + r;
        float4 v = make_float4(0.f, 0.f, 0.f, 0.f);
        if (rr >= 0 && rr < HH)              // wave-uniform branch
            v = *(const float4*)(ip + (long)rr * WW);
        if (r - 0 >= 0 && r - 0 < KS) { float w = W[r];     acc0.x += v.x*w; acc0.y += v.y*w; acc0.z += v.z*w; acc0.w += v.w*w; }
        if (r - 1 >= 0 && r - 1 < KS) { float w = W[r - 1]; acc1.x += v.x*w; acc1.y += v.y*w; acc1.z += v.z*w; acc1.w += v.w*w; }
        if (r - 2 >= 0 && r - 2 < KS) { float w = W[r - 2]; acc2.x += v.x*w; acc2.y += v.y*w; acc2.z += v.z*w; acc2.w += v.w*w; }
        if (r - 3 >= 0 && r - 3 < KS) { float w = W[r - 3]; acc3.x += v.x*w; acc3.y += v.y*w; acc3.z += v.z*w; acc3.w += v.w*w; }
    }
    *(float4*)&tile[(rg + 0) * LDSW + PAD + col4 * 4] = acc0;
    *(float4*)&tile[(rg + 1) * LDSW + PAD + col4 * 4] = acc1;
    *(float4*)&tile[(rg + 2) * LDSW + PAD + col4 * 4] = acc2;
    *(float4*)&tile[(rg + 3) * LDSW + PAD + col4 * 4] = acc3;

    __syncthreads();

    // ---- horizontal stage + clip: thread -> one f4 output per iteration ----
#pragma unroll
    for (int it = 0; it < 4; ++it) {
        int f = it * 256 + tid;              // f4 index in strip
        int c4 = f & 127;                    // consecutive lanes -> coalesced
        int row = f >> 7;
        // window starts at padded col c4*4 (= output col c4*4 - 12)
        const float* lp = &tile[row * LDSW + c4 * 4];
        float o0 = 0.f, o1 = 0.f, o2 = 0.f, o3 = 0.f;
#pragma unroll
        for (int q = 0; q < 7; ++q) {        // 7x ds_read_b128, 16B lane stride
            float4 v = *(const float4*)(lp + 4 * q);
            float vv[4] = {v.x, v.y, v.z, v.w};
#pragma unroll
            for (int e = 0; e < 4; ++e) {
                int wdx = 4 * q + e;         // window index 0..27
                if (wdx - 0 >= 0 && wdx - 0 < KS) o0 += vv[e] * W[wdx];
                if (wdx - 1 >= 0 && wdx - 1 < KS) o1 += vv[e] * W[wdx - 1];
                if (wdx - 2 >= 0 && wdx - 2 < KS) o2 += vv[e] * W[wdx - 2];
                if (wdx - 3 >= 0 && wdx - 3 < KS) o3 += vv[e] * W[wdx - 3];
            }
        }
        float4 ov = make_float4(clamp01(o0), clamp01(o1), clamp01(o2), clamp01(o3));
        // plain store: NT stores caused 6x write / 7x fetch HBM amplification (round 4)
        *(float4*)(obase + (long)(r0 + row) * WW + c4 * 4) = ov;
    }
}

extern "C" void kernel_launch(void* const* d_in, const int* in_sizes, int n_in,
                              void* d_out, int out_size, void* d_ws, size_t ws_size,
                              hipStream_t stream) {
    const float* x = (const float*)d_in[0];
    float* out = (float*)d_out;
    const int nwg = NB * CC * (HH / HT);   // 6144 blocks
    gblur_fused<<<nwg, 256, 0, stream>>>(x, out);
}

// Round 6
// 48.300 us; speedup vs baseline: 5.3087x; 5.3087x over previous
//
#include <hip/hip_runtime.h>

#define NB 32
#define CC 3
#define HH 512
#define WW 512
#define KS 25
#define PAD 12
#define HT 8                  // output rows per block (full 512-wide strip)
#define LDSW 536              // 12 halo + 512 + 12 halo floats per LDS row

__device__ __forceinline__ float clamp01(float v) {
    return fminf(fmaxf(v, 0.0f), 1.0f);
}

// launch_bounds(256,8) in round 4/5 forced VGPR=32 -> per-thread spills:
// WRITE_SIZE 98->597MB, FETCH 49->359MB, 5x slowdown. (256,4) caps at 128 VGPR.
__global__ __launch_bounds__(256, 4) void gblur_fused(const float* __restrict__ x,
                                                      float* __restrict__ out) {
    // weights as compile-time literals (indexed only by unrolled constants)
    constexpr float W[KS] = {
        0.02181520f, 0.02514307f, 0.02862302f, 0.03218484f, 0.03574584f,
        0.03921371f, 0.04249020f, 0.04547544f, 0.04807347f, 0.05019624f,
        0.05176967f, 0.05273727f, 0.05306384f, 0.05273727f, 0.05176967f,
        0.05019624f, 0.04807347f, 0.04547544f, 0.04249020f, 0.03921371f,
        0.03574584f, 0.03218484f, 0.02862302f, 0.02514307f, 0.02181520f};

    __shared__ float tile[HT * LDSW];   // 17,152 B

    int tid = threadIdx.x;

    // zero left/right halos: 8 rows x 24 floats = 192 writes
    if (tid < HT * 2 * PAD) {
        int r = tid / (2 * PAD);
        int k = tid - r * (2 * PAD);
        tile[r * LDSW + (k < PAD ? k : 512 + k)] = 0.0f;
    }

    // ---- block mapping with bijective XCD swizzle (6144 % 8 == 0) ----
    int b = blockIdx.x;
    const int nwg = NB * CC * (HH / HT);     // 6144
    int per = nwg >> 3;
    int swz = (b & 7) * per + (b >> 3);
    int plane = swz >> 6;                    // 64 strips per plane
    int strip = swz & 63;
    int r0 = strip * HT;

    const float* ibase = x + (long)plane * (HH * WW);
    float*       obase = out + (long)plane * (HH * WW);

    // ---- vertical stage: thread = (float4 col, 4-row group) ----
    int col4 = tid & 127;                    // consecutive lanes -> coalesced f4
    int rg = (tid >> 7) * 4;                 // 0 or 4; wave-uniform
    const float* ip = ibase + col4 * 4;

    float4 acc0 = make_float4(0.f, 0.f, 0.f, 0.f);
    float4 acc1 = acc0, acc2 = acc0, acc3 = acc0;

#pragma unroll
    for (int r = 0; r < 4 + KS - 1; ++r) {   // 28 input rows
        int rr = r0 + rg - PAD + r;
        float4 v = make_float4(0.f, 0.f, 0.f, 0.f);
        if (rr >= 0 && rr < HH)              // wave-uniform branch
            v = *(const float4*)(ip + (long)rr * WW);
        if (r - 0 >= 0 && r - 0 < KS) { float w = W[r];     acc0.x += v.x*w; acc0.y += v.y*w; acc0.z += v.z*w; acc0.w += v.w*w; }
        if (r - 1 >= 0 && r - 1 < KS) { float w = W[r - 1]; acc1.x += v.x*w; acc1.y += v.y*w; acc1.z += v.z*w; acc1.w += v.w*w; }
        if (r - 2 >= 0 && r - 2 < KS) { float w = W[r - 2]; acc2.x += v.x*w; acc2.y += v.y*w; acc2.z += v.z*w; acc2.w += v.w*w; }
        if (r - 3 >= 0 && r - 3 < KS) { float w = W[r - 3]; acc3.x += v.x*w; acc3.y += v.y*w; acc3.z += v.z*w; acc3.w += v.w*w; }
    }
    *(float4*)&tile[(rg + 0) * LDSW + PAD + col4 * 4] = acc0;
    *(float4*)&tile[(rg + 1) * LDSW + PAD + col4 * 4] = acc1;
    *(float4*)&tile[(rg + 2) * LDSW + PAD + col4 * 4] = acc2;
    *(float4*)&tile[(rg + 3) * LDSW + PAD + col4 * 4] = acc3;

    __syncthreads();

    // ---- horizontal stage + clip: thread -> one f4 output per iteration ----
#pragma unroll
    for (int it = 0; it < 4; ++it) {
        int f = it * 256 + tid;              // f4 index in strip
        int c4 = f & 127;                    // consecutive lanes -> coalesced
        int row = f >> 7;
        // window starts at padded col c4*4 (= output col c4*4 - 12)
        const float* lp = &tile[row * LDSW + c4 * 4];
        float o0 = 0.f, o1 = 0.f, o2 = 0.f, o3 = 0.f;
#pragma unroll
        for (int q = 0; q < 7; ++q) {        // 7x ds_read_b128, 16B lane stride
            float4 v = *(const float4*)(lp + 4 * q);
            float vv[4] = {v.x, v.y, v.z, v.w};
#pragma unroll
            for (int e = 0; e < 4; ++e) {
                int wdx = 4 * q + e;         // window index 0..27
                if (wdx - 0 >= 0 && wdx - 0 < KS) o0 += vv[e] * W[wdx];
                if (wdx - 1 >= 0 && wdx - 1 < KS) o1 += vv[e] * W[wdx - 1];
                if (wdx - 2 >= 0 && wdx - 2 < KS) o2 += vv[e] * W[wdx - 2];
                if (wdx - 3 >= 0 && wdx - 3 < KS) o3 += vv[e] * W[wdx - 3];
            }
        }
        float4 ov = make_float4(clamp01(o0), clamp01(o1), clamp01(o2), clamp01(o3));
        *(float4*)(obase + (long)(r0 + row) * WW + c4 * 4) = ov;
    }
}

extern "C" void kernel_launch(void* const* d_in, const int* in_sizes, int n_in,
                              void* d_out, int out_size, void* d_ws, size_t ws_size,
                              hipStream_t stream) {
    const float* x = (const float*)d_in[0];
    float* out = (float*)d_out;
    const int nwg = NB * CC * (HH / HT);   // 6144 blocks
    gblur_fused<<<nwg, 256, 0, stream>>>(x, out);
}

// Round 7
// 43.606 us; speedup vs baseline: 5.8803x; 1.1077x over previous
//
#include <hip/hip_runtime.h>

#define NB 32
#define CC 3
#define HH 512
#define WW 512
#define KS 25
#define PAD 12
#define HT 8                  // output rows per block (full 512-wide strip)
#define LDSW 536              // 12 halo + 512 + 12 halo floats per LDS row

__device__ __forceinline__ float clamp01(float v) {
    return fminf(fmaxf(v, 0.0f), 1.0f);
}

// EDGE=false: strips 2..61, no bounds checks anywhere (94% of blocks).
template<bool EDGE>
__device__ __forceinline__ void blur_body(const float* __restrict__ ibase,
                                          float* __restrict__ obase,
                                          int r0, int tid, float* tile) {
    constexpr float W[KS] = {
        0.02181520f, 0.02514307f, 0.02862302f, 0.03218484f, 0.03574584f,
        0.03921371f, 0.04249020f, 0.04547544f, 0.04807347f, 0.05019624f,
        0.05176967f, 0.05273727f, 0.05306384f, 0.05273727f, 0.05176967f,
        0.05019624f, 0.04807347f, 0.04547544f, 0.04249020f, 0.03921371f,
        0.03574584f, 0.03218484f, 0.02862302f, 0.02514307f, 0.02181520f};

    // zero left/right halos: 8 rows x 24 floats
    if (tid < HT * 2 * PAD) {
        int r = tid / (2 * PAD);
        int k = tid - r * (2 * PAD);
        tile[r * LDSW + (k < PAD ? k : 512 + k)] = 0.0f;
    }

    // ---- vertical: thread owns float2-column tid for ALL 8 rows ----
    // 32 sliding-window loads; each row of the block window loaded ONCE.
    const float* ip = ibase + tid * 2;
    float2 acc[HT];
#pragma unroll
    for (int j = 0; j < HT; ++j) acc[j] = make_float2(0.f, 0.f);

#pragma unroll
    for (int r = 0; r < HT + KS - 1; ++r) {      // 32 input rows
        int rr = r0 - PAD + r;
        float2 v = make_float2(0.f, 0.f);
        if (!EDGE || (rr >= 0 && rr < HH))       // compile-time true for interior
            v = *(const float2*)(ip + (long)rr * WW);
#pragma unroll
        for (int j = 0; j < HT; ++j) {
            int t = r - j;                       // compile-time pruned taps
            if (t >= 0 && t < KS) {
                acc[j].x += v.x * W[t];
                acc[j].y += v.y * W[t];
            }
        }
    }
#pragma unroll
    for (int j = 0; j < HT; ++j)
        *(float2*)&tile[j * LDSW + PAD + tid * 2] = acc[j];

    __syncthreads();

    // ---- horizontal + clip: thread -> one f4 output per iteration ----
#pragma unroll
    for (int it = 0; it < 4; ++it) {
        int f = it * 256 + tid;                  // f4 index in strip
        int c4 = f & 127;                        // consecutive lanes -> coalesced
        int row = f >> 7;
        const float* lp = &tile[row * LDSW + c4 * 4];  // window start (out col - 12)
        float o0 = 0.f, o1 = 0.f, o2 = 0.f, o3 = 0.f;
#pragma unroll
        for (int q = 0; q < 7; ++q) {            // 7x ds_read_b128
            float4 v = *(const float4*)(lp + 4 * q);
            float vv[4] = {v.x, v.y, v.z, v.w};
#pragma unroll
            for (int e = 0; e < 4; ++e) {
                int wdx = 4 * q + e;             // window index 0..27
                if (wdx - 0 >= 0 && wdx - 0 < KS) o0 += vv[e] * W[wdx];
                if (wdx - 1 >= 0 && wdx - 1 < KS) o1 += vv[e] * W[wdx - 1];
                if (wdx - 2 >= 0 && wdx - 2 < KS) o2 += vv[e] * W[wdx - 2];
                if (wdx - 3 >= 0 && wdx - 3 < KS) o3 += vv[e] * W[wdx - 3];
            }
        }
        float4 ov = make_float4(clamp01(o0), clamp01(o1), clamp01(o2), clamp01(o3));
        *(float4*)(obase + (long)(r0 + row) * WW + c4 * 4) = ov;
    }
}

// (256,8) forced VGPR=32 -> spills (WRITE 98->597MB, 5x slower). Keep (256,4).
__global__ __launch_bounds__(256, 4) void gblur_fused(const float* __restrict__ x,
                                                      float* __restrict__ out) {
    __shared__ float tile[HT * LDSW];            // 17,152 B

    int tid = threadIdx.x;

    // ---- block mapping with bijective XCD swizzle (6144 % 8 == 0) ----
    int b = blockIdx.x;
    const int nwg = NB * CC * (HH / HT);         // 6144
    int per = nwg >> 3;
    int swz = (b & 7) * per + (b >> 3);
    int plane = swz >> 6;                        // 64 strips per plane
    int strip = swz & 63;
    int r0 = strip * HT;

    const float* ibase = x + (long)plane * (HH * WW);
    float*       obase = out + (long)plane * (HH * WW);

    // block-uniform edge test: window [r0-12, r0+19] inside [0,511]?
    if (r0 >= PAD && r0 <= HH - HT - PAD)
        blur_body<false>(ibase, obase, r0, tid, tile);
    else
        blur_body<true>(ibase, obase, r0, tid, tile);
}

extern "C" void kernel_launch(void* const* d_in, const int* in_sizes, int n_in,
                              void* d_out, int out_size, void* d_ws, size_t ws_size,
                              hipStream_t stream) {
    const float* x = (const float*)d_in[0];
    float* out = (float*)d_out;
    const int nwg = NB * CC * (HH / HT);         // 6144 blocks
    gblur_fused<<<nwg, 256, 0, stream>>>(x, out);
}